// Round 14
// baseline (248.664 us; speedup 1.0000x reference)
//
#include <hip/hip_runtime.h>
#include <math.h>

#define NN 50000
#define NE 1600000
#define NBIN 391        // ceil(NN/128), 128 nodes per bin
#define BINCAP 4608     // mean 4092, sigma ~64 -> +8 sigma
#define EPB 8192        // edges per block in scatter role
#define SCAT_B ((NE + EPB - 1) / EPB)       // 196
#define PREP_B (2 * 512 * 128 / 512)        // 256
#define GEMM_B ((NN + 127) / 128)           // 391 (128-row tiles)

typedef __attribute__((ext_vector_type(8))) short bf16x8;
typedef __attribute__((ext_vector_type(4))) float f32x4;
typedef __attribute__((ext_vector_type(2))) float f32x2;

struct WPtrs { const float* p[16]; };

__device__ __forceinline__ ushort f2bf(float f) {
  union { float f; unsigned u; } a; a.f = f;
  return (ushort)((a.u + 0x7fffu + ((a.u >> 16) & 1u)) >> 16);
}
__device__ __forceinline__ f32x2 unp2(unsigned u) {   // 2 bf16 -> 2 f32
  f32x2 r;
  r.x = __uint_as_float(u << 16);
  r.y = __uint_as_float(u & 0xffff0000u);
  return r;
}

// ---------------------------------------------------------------------------
// GEMM body: A[128 rows,128] @ Wt^T + bias (8 waves, LDS XOR-swizzled A-tile)
// ---------------------------------------------------------------------------
template <int AF32>
__device__ __forceinline__ void gemm_body(
    const void* __restrict__ Av, const ushort* __restrict__ Wt,
    const float* __restrict__ bias,
    ushort* __restrict__ q_bf, ushort* __restrict__ s_bf,
    unsigned char* __restrict__ kv8, int M, char* As, int bid)
{
  const int t = threadIdx.x;
  const int m0 = bid * 128;

  #pragma unroll
  for (int it = 0; it < 4; ++it) {
    const int L = it * 4096 + t * 8;
    const int row = L >> 7, col = L & 127;
    const int grow = m0 + row;
    uint4 pk = make_uint4(0, 0, 0, 0);
    if (grow < M) {
      if (AF32) {
        const float* ap = (const float*)Av + (size_t)grow * 128 + col;
        const float4 a = *(const float4*)ap;
        const float4 b = *(const float4*)(ap + 4);
        pk.x = (unsigned)f2bf(a.x) | ((unsigned)f2bf(a.y) << 16);
        pk.y = (unsigned)f2bf(a.z) | ((unsigned)f2bf(a.w) << 16);
        pk.z = (unsigned)f2bf(b.x) | ((unsigned)f2bf(b.y) << 16);
        pk.w = (unsigned)f2bf(b.z) | ((unsigned)f2bf(b.w) << 16);
      } else {
        pk = *(const uint4*)((const ushort*)Av + (size_t)grow * 128 + col);
      }
    }
    const int byte = (row * 256 + col * 2) ^ ((row & 7) << 4);
    *(uint4*)(As + byte) = pk;
  }
  __syncthreads();

  const int w = t >> 6, l = t & 63, lr = l & 15, lk = l >> 4;
  const int nb = w * 64;
  const int g = w >> 1;   // 0=q 1=k 2=v 3=s (wave-uniform)

  bf16x8 bfr[4][4];
  #pragma unroll
  for (int ni = 0; ni < 4; ++ni)
    #pragma unroll
    for (int kk = 0; kk < 4; ++kk)
      bfr[ni][kk] = *(const bf16x8*)(Wt + (size_t)(nb + ni * 16 + lr) * 128 + kk * 32 + lk * 8);
  float4 b4[4];
  #pragma unroll
  for (int ni = 0; ni < 4; ++ni)
    b4[ni] = *(const float4*)(bias + nb + ni * 16 + lk * 4);

  #pragma unroll
  for (int mi = 0; mi < 8; ++mi) {
    const int r = mi * 16 + lr;
    bf16x8 af[4];
    #pragma unroll
    for (int kk = 0; kk < 4; ++kk) {
      const int byte = (r * 256 + (kk * 32 + lk * 8) * 2) ^ ((r & 7) << 4);
      af[kk] = *(const bf16x8*)(As + byte);
    }
    f32x4 acc[4];
    #pragma unroll
    for (int ni = 0; ni < 4; ++ni) acc[ni] = (f32x4){0.f, 0.f, 0.f, 0.f};
    #pragma unroll
    for (int kk = 0; kk < 4; ++kk)
      #pragma unroll
      for (int ni = 0; ni < 4; ++ni)
        acc[ni] = __builtin_amdgcn_mfma_f32_16x16x32_bf16(bfr[ni][kk], af[kk], acc[ni], 0, 0, 0);

    const int row = m0 + mi * 16 + lr;
    if (row < M) {
      #pragma unroll
      for (int ni = 0; ni < 4; ++ni) {
        const float v0 = acc[ni][0] + b4[ni].x;
        const float v1 = acc[ni][1] + b4[ni].y;
        const float v2 = acc[ni][2] + b4[ni].z;
        const float v3 = acc[ni][3] + b4[ni].w;
        const int c = (nb & 127) + ni * 16 + lk * 4;
        if (g == 0 || g == 3) {
          ushort4 o4;
          o4.x = f2bf(v0); o4.y = f2bf(v1); o4.z = f2bf(v2); o4.w = f2bf(v3);
          ushort* dstp = (g == 0) ? q_bf : s_bf;
          *(ushort4*)(dstp + (size_t)row * 128 + c) = o4;
        } else {
          unsigned u = __builtin_amdgcn_cvt_pk_fp8_f32(v0, v1, 0, false);
          u = __builtin_amdgcn_cvt_pk_fp8_f32(v2, v3, u, true);
          *(unsigned*)(kv8 + (size_t)row * 256 + (g == 2 ? 128 : 0) + c) = u;
        }
      }
    }
  }
}

// ---------------------------------------------------------------------------
// FAT 1: blocks [0,SCAT_B) = binned edge scatter; [SCAT_B,+PREP_B) = weight prep
// ---------------------------------------------------------------------------
__global__ __launch_bounds__(512) void fat_scatter_prep(
    const int* __restrict__ src, const int* __restrict__ dst,
    int* __restrict__ binCnt, unsigned* __restrict__ binbuf,
    WPtrs wp,
    ushort* __restrict__ Wt0, ushort* __restrict__ Wt1,
    float* __restrict__ bias0, float* __restrict__ bias1)
{
  const int t = threadIdx.x;
  if (blockIdx.x < SCAT_B) {
    __shared__ int hist[NBIN], base[NBIN];
    const int e0 = blockIdx.x * EPB;
    const int e1 = min(e0 + EPB, NE);
    for (int i = t; i < NBIN; i += 512) hist[i] = 0;
    __syncthreads();
    for (int e = e0 + t; e < e1; e += 512) atomicAdd(&hist[dst[e] >> 7], 1);
    __syncthreads();
    for (int i = t; i < NBIN; i += 512) {
      const int c = hist[i];
      base[i] = (c > 0) ? atomicAdd(&binCnt[i], c) : 0;
      hist[i] = 0;   // reuse as local cursor
    }
    __syncthreads();
    for (int e = e0 + t; e < e1; e += 512) {
      const int d = dst[e], b = d >> 7;
      const int p = base[b] + atomicAdd(&hist[b], 1);
      if (p < BINCAP)
        binbuf[(size_t)b * BINCAP + p] = (unsigned)src[e] | ((unsigned)(d & 127) << 16);
    }
  } else {
    const int idx = (blockIdx.x - SCAT_B) * 512 + t;   // < 2*512*128
    const int layer = idx >> 16;
    const int li = idx & 0xFFFF;
    const int n = li >> 7, k = li & 127, g = n >> 7, nl = n & 127;
    const float* W = wp.p[layer * 8 + g];
    (layer == 0 ? Wt0 : Wt1)[li] = f2bf(W[k * 128 + nl]);
    if (li < 512) {
      const int gb = li >> 7, nbv = li & 127;
      const float* B = wp.p[layer * 8 + 4 + gb];
      (layer == 0 ? bias0 : bias1)[li] = B[nbv];
    }
  }
}

// ---------------------------------------------------------------------------
// FAT 2: blocks [0,GEMM_B) = layer-0 GEMM (A = x f32); [GEMM_B,+NBIN) = bin_fill
// ---------------------------------------------------------------------------
__global__ __launch_bounds__(512) void fat_gemm_fill(
    const float* __restrict__ x, const ushort* __restrict__ Wt0,
    const float* __restrict__ bias0,
    ushort* __restrict__ q_bf, ushort* __restrict__ s_bf,
    unsigned char* __restrict__ kv8,
    const unsigned* __restrict__ binbuf, const int* __restrict__ binCnt,
    int* __restrict__ row_start, int* __restrict__ colv)
{
  __shared__ char smem[128 * 256];
  const int t = threadIdx.x;
  if (blockIdx.x < GEMM_B) {
    gemm_body<1>(x, Wt0, bias0, q_bf, s_bf, kv8, NN, smem, blockIdx.x);
    return;
  }
  // ---- bin_fill role ----
  int* hist  = (int*)smem;          // 128
  int* scanb = hist + 128;          // 128
  int* cur   = scanb + 128;         // 128
  int* wred  = cur + 128;           // 8
  const int b = blockIdx.x - GEMM_B;
  int part = 0;
  for (int i = t; i < b; i += 512) part += min(binCnt[i], BINCAP);
  #pragma unroll
  for (int o = 32; o; o >>= 1) part += __shfl_xor(part, o, 64);
  if ((t & 63) == 0) wred[t >> 6] = part;
  const int n = min(binCnt[b], BINCAP);
  const unsigned* __restrict__ buf = binbuf + (size_t)b * BINCAP;
  if (t < 128) hist[t] = 0;
  __syncthreads();
  int binBase = 0;
  #pragma unroll
  for (int i = 0; i < 8; ++i) binBase += wred[i];
  if (b == NBIN - 1 && t == 0) row_start[NN] = binBase + n;
  for (int i = t; i < n; i += 512) atomicAdd(&hist[(buf[i] >> 16) & 127], 1);
  __syncthreads();
  if (t < 128) scanb[t] = hist[t];
  __syncthreads();
  for (int off = 1; off < 128; off <<= 1) {
    int a = (t >= off && t < 128) ? scanb[t - off] : 0;
    __syncthreads();
    if (t < 128) scanb[t] += a;
    __syncthreads();
  }
  if (t < 128) {
    const int node = b * 128 + t;
    const int base = binBase + scanb[t] - hist[t];   // exclusive
    if (node < NN) row_start[node] = base;
    cur[t] = base;
  }
  __syncthreads();
  for (int i = t; i < n; i += 512) {
    const unsigned v = buf[i];
    const int pos = atomicAdd(&cur[(v >> 16) & 127], 1);
    colv[pos] = (int)(v & 0xFFFFu);
  }
}

// standalone layer-1 GEMM (A = h bf16)
__global__ __launch_bounds__(512) void gemm_v2(
    const ushort* __restrict__ A, const ushort* __restrict__ Wt,
    const float* __restrict__ bias,
    ushort* __restrict__ q_bf, ushort* __restrict__ s_bf,
    unsigned char* __restrict__ kv8)
{
  __shared__ char As[128 * 256];
  gemm_body<0>(A, Wt, bias, q_bf, s_bf, kv8, NN, As, blockIdx.x);
}

// ---------------------------------------------------------------------------
// Fused online attention + skip + LayerNorm. ONE node per wave (unchanged
// per-wave code from r13 best), but 1024-thread blocks (16 waves = 16 nodes):
// tests the CP-dispatch-rate hypothesis — 12500 tiny blocks retiring at
// ~195 WG/us appeared to outrun workgroup dispatch, capping occupancy at
// ~54%. 3125 blocks cut CP pressure 4x; waves are independent (no sync).
// ---------------------------------------------------------------------------
template <int WRITE_BF16>
__global__ __launch_bounds__(1024) void edge_attn(
    const ushort* __restrict__ q_bf, const ushort* __restrict__ s_bf,
    const unsigned char* __restrict__ kv8,
    const int* __restrict__ row_start, const int* __restrict__ colv,
    const float* __restrict__ gamma, const float* __restrict__ beta,
    float* __restrict__ out_f, ushort* __restrict__ out_bf)
{
  const int wave = threadIdx.x >> 6, lane = threadIdx.x & 63;
  const int e8 = lane >> 3, l8 = lane & 7;
  const int n = blockIdx.x * 16 + wave;
  if (n >= NN) return;
  const int beg = row_start[n];
  const int deg = row_start[n + 1] - beg;

  int sn_own = 0;
  const bool small = (deg <= 64);
  if (small && deg > 0) sn_own = colv[beg + min(lane, deg - 1)];

  f32x2 qv[8];
  {
    const uint4 qa = *(const uint4*)(q_bf + (size_t)n * 128 + l8 * 16);
    const uint4 qb = *(const uint4*)(q_bf + (size_t)n * 128 + l8 * 16 + 8);
    qv[0] = unp2(qa.x); qv[1] = unp2(qa.y); qv[2] = unp2(qa.z); qv[3] = unp2(qa.w);
    qv[4] = unp2(qb.x); qv[5] = unp2(qb.y); qv[6] = unp2(qb.z); qv[7] = unp2(qb.w);
  }

  f32x2 acc2[8];
  #pragma unroll
  for (int j = 0; j < 8; ++j) acc2[j] = (f32x2){0.f, 0.f};
  float den = 0.f;

  if (deg > 0) {
    // prologue: load group 0
    int ii = min(e8, deg - 1);
    int sn = small ? __shfl(sn_own, ii, 64) : colv[beg + ii];
    const unsigned char* kvp = kv8 + (size_t)sn * 256 + l8 * 16;
    uint4 kw = *(const uint4*)kvp;
    uint4 vw = *(const uint4*)(kvp + 128);

    for (int base = 0; base < deg; base += 8) {
      // prefetch group base+8 (uniform gate -> no wasted traffic)
      uint4 kwn = kw, vwn = vw;
      if (base + 8 < deg) {
        const int iN = min(base + 8 + e8, deg - 1);
        const int snn = small ? __shfl(sn_own, iN, 64) : colv[beg + iN];
        const unsigned char* kvpn = kv8 + (size_t)snn * 256 + l8 * 16;
        kwn = *(const uint4*)kvpn;
        vwn = *(const uint4*)(kvpn + 128);
      }
      // compute current group
      const int i = base + e8;
      f32x2 p2 = __builtin_amdgcn_cvt_pk_f32_fp8((int)kw.x, false) * qv[0];
      p2 += __builtin_amdgcn_cvt_pk_f32_fp8((int)kw.x, true)  * qv[1];
      p2 += __builtin_amdgcn_cvt_pk_f32_fp8((int)kw.y, false) * qv[2];
      p2 += __builtin_amdgcn_cvt_pk_f32_fp8((int)kw.y, true)  * qv[3];
      p2 += __builtin_amdgcn_cvt_pk_f32_fp8((int)kw.z, false) * qv[4];
      p2 += __builtin_amdgcn_cvt_pk_f32_fp8((int)kw.z, true)  * qv[5];
      p2 += __builtin_amdgcn_cvt_pk_f32_fp8((int)kw.w, false) * qv[6];
      p2 += __builtin_amdgcn_cvt_pk_f32_fp8((int)kw.w, true)  * qv[7];
      float p = p2.x + p2.y;
      p += __shfl_xor(p, 1, 64);
      p += __shfl_xor(p, 2, 64);
      const float e = (i < deg) ? __expf(p * 0.125f) : 0.f;
      den += e;
      const f32x2 e2 = (f32x2){e, e};
      acc2[0] += __builtin_amdgcn_cvt_pk_f32_fp8((int)vw.x, false) * e2;
      acc2[1] += __builtin_amdgcn_cvt_pk_f32_fp8((int)vw.x, true)  * e2;
      acc2[2] += __builtin_amdgcn_cvt_pk_f32_fp8((int)vw.y, false) * e2;
      acc2[3] += __builtin_amdgcn_cvt_pk_f32_fp8((int)vw.y, true)  * e2;
      acc2[4] += __builtin_amdgcn_cvt_pk_f32_fp8((int)vw.z, false) * e2;
      acc2[5] += __builtin_amdgcn_cvt_pk_f32_fp8((int)vw.z, true)  * e2;
      acc2[6] += __builtin_amdgcn_cvt_pk_f32_fp8((int)vw.w, false) * e2;
      acc2[7] += __builtin_amdgcn_cvt_pk_f32_fp8((int)vw.w, true)  * e2;
      kw = kwn; vw = vwn;
    }
  }

  #pragma unroll
  for (int off = 8; off <= 32; off <<= 1) {
    den += __shfl_xor(den, off, 64);
    #pragma unroll
    for (int j = 0; j < 8; ++j) {
      acc2[j].x += __shfl_xor(acc2[j].x, off, 64);
      acc2[j].y += __shfl_xor(acc2[j].y, off, 64);
    }
  }

  const float rden = (deg > 0) ? 1.f / den : 0.f;
  float o[16], s1 = 0.f, s2 = 0.f;
  {
    const uint4 ra = *(const uint4*)(s_bf + (size_t)n * 128 + l8 * 16);
    const uint4 rb = *(const uint4*)(s_bf + (size_t)n * 128 + l8 * 16 + 8);
    f32x2 sv[8];
    sv[0] = unp2(ra.x); sv[1] = unp2(ra.y); sv[2] = unp2(ra.z); sv[3] = unp2(ra.w);
    sv[4] = unp2(rb.x); sv[5] = unp2(rb.y); sv[6] = unp2(rb.z); sv[7] = unp2(rb.w);
    #pragma unroll
    for (int j = 0; j < 8; ++j) {
      const float a = acc2[j].x * rden + sv[j].x;
      const float b = acc2[j].y * rden + sv[j].y;
      o[2 * j] = a; o[2 * j + 1] = b;
      s1 += a + b; s2 += a * a + b * b;
    }
  }
  #pragma unroll
  for (int off = 1; off <= 4; off <<= 1) {
    s1 += __shfl_xor(s1, off, 64);
    s2 += __shfl_xor(s2, off, 64);
  }
  const float mean = s1 * (1.f / 128.f);
  const float var  = s2 * (1.f / 128.f) - mean * mean;
  const float rs   = rsqrtf(fmaxf(var, 0.f) + 1e-5f);
  if (e8 == 0) {
    const int cbase = l8 * 16;
    #pragma unroll
    for (int jj = 0; jj < 4; ++jj) {
      const float4 g4 = *(const float4*)(gamma + cbase + jj * 4);
      const float4 b4 = *(const float4*)(beta + cbase + jj * 4);
      const float r0 = g4.x * ((o[jj*4+0] - mean) * rs) + b4.x;
      const float r1 = g4.y * ((o[jj*4+1] - mean) * rs) + b4.y;
      const float r2 = g4.z * ((o[jj*4+2] - mean) * rs) + b4.z;
      const float r3 = g4.w * ((o[jj*4+3] - mean) * rs) + b4.w;
      if (WRITE_BF16) {
        ushort4 u4; u4.x = f2bf(r0); u4.y = f2bf(r1); u4.z = f2bf(r2); u4.w = f2bf(r3);
        *(ushort4*)(out_bf + (size_t)n * 128 + cbase + jj * 4) = u4;
      } else {
        *(float4*)(out_f + (size_t)n * 128 + cbase + jj * 4) = make_float4(r0, r1, r2, r3);
      }
    }
  }
}

// ---------------------------------------------------------------------------
extern "C" void kernel_launch(void* const* d_in, const int* in_sizes, int n_in,
                              void* d_out, int out_size, void* d_ws, size_t ws_size,
                              hipStream_t stream)
{
  const float* x  = (const float*)d_in[0];
  const int*   ei = (const int*)d_in[1];
  const float* P[20];
  for (int i = 0; i < 20; ++i) P[i] = (const float*)d_in[2 + i];

  char* w = (char*)d_ws;
  ushort* q_bf = (ushort*)w; w += (size_t)NN * 128 * 2;          // 12.8 MB
  ushort* s_bf = (ushort*)w; w += (size_t)NN * 128 * 2;          // 12.8 MB
  unsigned char* kv8 = (unsigned char*)w; w += (size_t)NN * 256; // 12.8 MB
  ushort* h_bf = (ushort*)w; w += (size_t)NN * 128 * 2;          // 12.8 MB
  unsigned* binbuf = (unsigned*)w; w += (size_t)NBIN * BINCAP * 4; // 7.2 MB
  int* colv = (int*)w;      w += (size_t)NE * 4;                 // 6.4 MB
  ushort* Wt0 = (ushort*)w; w += (size_t)512 * 128 * 2;
  ushort* Wt1 = (ushort*)w; w += (size_t)512 * 128 * 2;
  float* bias0 = (float*)w; w += 512 * 4;
  float* bias1 = (float*)w; w += 512 * 4;
  int* row_start = (int*)w; w += (size_t)(NN + 1) * 4;
  int* binCnt = (int*)w;    w += (size_t)NBIN * 4;

  const int* srcv = ei;
  const int* dstv = ei + NE;

  WPtrs wp;
  for (int i = 0; i < 8; ++i)  wp.p[i] = P[i];          // layer 0
  for (int i = 0; i < 8; ++i)  wp.p[8 + i] = P[10 + i]; // layer 1

  hipMemsetAsync(binCnt, 0, (size_t)NBIN * 4, stream);

  // FAT1: edge scatter || weight prep
  fat_scatter_prep<<<SCAT_B + PREP_B, 512, 0, stream>>>(
      srcv, dstv, binCnt, binbuf, wp, Wt0, Wt1, bias0, bias1);

  // FAT2: layer-0 GEMM || CSR fill
  fat_gemm_fill<<<GEMM_B + NBIN, 512, 0, stream>>>(
      x, Wt0, bias0, q_bf, s_bf, kv8, binbuf, binCnt, row_start, colv);

  const int agrid = (NN + 15) / 16;   // 16 waves/block, 1 node per wave

  edge_attn<1><<<agrid, 1024, 0, stream>>>(q_bf, s_bf, kv8, row_start, colv,
                                           P[8], P[9], nullptr, h_bf);
  gemm_v2<<<GEMM_B, 512, 0, stream>>>(h_bf, Wt1, bias1, q_bf, s_bf, kv8);
  edge_attn<0><<<agrid, 1024, 0, stream>>>(q_bf, s_bf, kv8, row_start, colv,
                                           P[18], P[19], (float*)d_out, nullptr);
}

// Round 15
// 205.673 us; speedup vs baseline: 1.2090x; 1.2090x over previous
//
#include <hip/hip_runtime.h>
#include <math.h>

#define NN 50000
#define NE 1600000
#define NBIN 391        // ceil(NN/128), 128 nodes per bin
#define BINCAP 4608     // mean 4092, sigma ~64 -> +8 sigma
#define EPB 8192        // edges per block in scatter role
#define SCAT_B ((NE + EPB - 1) / EPB)       // 196
#define PREP_B (2 * 512 * 128 / 512)        // 256
#define GEMM_B ((NN + 127) / 128)           // 391 (128-row tiles)

typedef __attribute__((ext_vector_type(8))) short bf16x8;
typedef __attribute__((ext_vector_type(4))) float f32x4;
typedef __attribute__((ext_vector_type(2))) float f32x2;

struct WPtrs { const float* p[16]; };

__device__ __forceinline__ ushort f2bf(float f) {
  union { float f; unsigned u; } a; a.f = f;
  return (ushort)((a.u + 0x7fffu + ((a.u >> 16) & 1u)) >> 16);
}
__device__ __forceinline__ f32x2 unp2(unsigned u) {   // 2 bf16 -> 2 f32
  f32x2 r;
  r.x = __uint_as_float(u << 16);
  r.y = __uint_as_float(u & 0xffff0000u);
  return r;
}

// ---------------------------------------------------------------------------
// GEMM body: A[128 rows,128] @ Wt^T + bias (8 waves, LDS XOR-swizzled A-tile)
// ---------------------------------------------------------------------------
template <int AF32>
__device__ __forceinline__ void gemm_body(
    const void* __restrict__ Av, const ushort* __restrict__ Wt,
    const float* __restrict__ bias,
    ushort* __restrict__ q_bf, ushort* __restrict__ s_bf,
    unsigned char* __restrict__ kv8, int M, char* As, int bid)
{
  const int t = threadIdx.x;
  const int m0 = bid * 128;

  #pragma unroll
  for (int it = 0; it < 4; ++it) {
    const int L = it * 4096 + t * 8;
    const int row = L >> 7, col = L & 127;
    const int grow = m0 + row;
    uint4 pk = make_uint4(0, 0, 0, 0);
    if (grow < M) {
      if (AF32) {
        const float* ap = (const float*)Av + (size_t)grow * 128 + col;
        const float4 a = *(const float4*)ap;
        const float4 b = *(const float4*)(ap + 4);
        pk.x = (unsigned)f2bf(a.x) | ((unsigned)f2bf(a.y) << 16);
        pk.y = (unsigned)f2bf(a.z) | ((unsigned)f2bf(a.w) << 16);
        pk.z = (unsigned)f2bf(b.x) | ((unsigned)f2bf(b.y) << 16);
        pk.w = (unsigned)f2bf(b.z) | ((unsigned)f2bf(b.w) << 16);
      } else {
        pk = *(const uint4*)((const ushort*)Av + (size_t)grow * 128 + col);
      }
    }
    const int byte = (row * 256 + col * 2) ^ ((row & 7) << 4);
    *(uint4*)(As + byte) = pk;
  }
  __syncthreads();

  const int w = t >> 6, l = t & 63, lr = l & 15, lk = l >> 4;
  const int nb = w * 64;
  const int g = w >> 1;   // 0=q 1=k 2=v 3=s (wave-uniform)

  bf16x8 bfr[4][4];
  #pragma unroll
  for (int ni = 0; ni < 4; ++ni)
    #pragma unroll
    for (int kk = 0; kk < 4; ++kk)
      bfr[ni][kk] = *(const bf16x8*)(Wt + (size_t)(nb + ni * 16 + lr) * 128 + kk * 32 + lk * 8);
  float4 b4[4];
  #pragma unroll
  for (int ni = 0; ni < 4; ++ni)
    b4[ni] = *(const float4*)(bias + nb + ni * 16 + lk * 4);

  #pragma unroll
  for (int mi = 0; mi < 8; ++mi) {
    const int r = mi * 16 + lr;
    bf16x8 af[4];
    #pragma unroll
    for (int kk = 0; kk < 4; ++kk) {
      const int byte = (r * 256 + (kk * 32 + lk * 8) * 2) ^ ((r & 7) << 4);
      af[kk] = *(const bf16x8*)(As + byte);
    }
    f32x4 acc[4];
    #pragma unroll
    for (int ni = 0; ni < 4; ++ni) acc[ni] = (f32x4){0.f, 0.f, 0.f, 0.f};
    #pragma unroll
    for (int kk = 0; kk < 4; ++kk)
      #pragma unroll
      for (int ni = 0; ni < 4; ++ni)
        acc[ni] = __builtin_amdgcn_mfma_f32_16x16x32_bf16(bfr[ni][kk], af[kk], acc[ni], 0, 0, 0);

    const int row = m0 + mi * 16 + lr;
    if (row < M) {
      #pragma unroll
      for (int ni = 0; ni < 4; ++ni) {
        const float v0 = acc[ni][0] + b4[ni].x;
        const float v1 = acc[ni][1] + b4[ni].y;
        const float v2 = acc[ni][2] + b4[ni].z;
        const float v3 = acc[ni][3] + b4[ni].w;
        const int c = (nb & 127) + ni * 16 + lk * 4;
        if (g == 0 || g == 3) {
          ushort4 o4;
          o4.x = f2bf(v0); o4.y = f2bf(v1); o4.z = f2bf(v2); o4.w = f2bf(v3);
          ushort* dstp = (g == 0) ? q_bf : s_bf;
          *(ushort4*)(dstp + (size_t)row * 128 + c) = o4;
        } else {
          unsigned u = __builtin_amdgcn_cvt_pk_fp8_f32(v0, v1, 0, false);
          u = __builtin_amdgcn_cvt_pk_fp8_f32(v2, v3, u, true);
          *(unsigned*)(kv8 + (size_t)row * 256 + (g == 2 ? 128 : 0) + c) = u;
        }
      }
    }
  }
}

// ---------------------------------------------------------------------------
// FAT 1: blocks [0,SCAT_B) = binned edge scatter; [SCAT_B,+PREP_B) = weight prep
// ---------------------------------------------------------------------------
__global__ __launch_bounds__(512) void fat_scatter_prep(
    const int* __restrict__ src, const int* __restrict__ dst,
    int* __restrict__ binCnt, unsigned* __restrict__ binbuf,
    WPtrs wp,
    ushort* __restrict__ Wt0, ushort* __restrict__ Wt1,
    float* __restrict__ bias0, float* __restrict__ bias1)
{
  const int t = threadIdx.x;
  if (blockIdx.x < SCAT_B) {
    __shared__ int hist[NBIN], base[NBIN];
    const int e0 = blockIdx.x * EPB;
    const int e1 = min(e0 + EPB, NE);
    for (int i = t; i < NBIN; i += 512) hist[i] = 0;
    __syncthreads();
    for (int e = e0 + t; e < e1; e += 512) atomicAdd(&hist[dst[e] >> 7], 1);
    __syncthreads();
    for (int i = t; i < NBIN; i += 512) {
      const int c = hist[i];
      base[i] = (c > 0) ? atomicAdd(&binCnt[i], c) : 0;
      hist[i] = 0;   // reuse as local cursor
    }
    __syncthreads();
    for (int e = e0 + t; e < e1; e += 512) {
      const int d = dst[e], b = d >> 7;
      const int p = base[b] + atomicAdd(&hist[b], 1);
      if (p < BINCAP)
        binbuf[(size_t)b * BINCAP + p] = (unsigned)src[e] | ((unsigned)(d & 127) << 16);
    }
  } else {
    const int idx = (blockIdx.x - SCAT_B) * 512 + t;   // < 2*512*128
    const int layer = idx >> 16;
    const int li = idx & 0xFFFF;
    const int n = li >> 7, k = li & 127, g = n >> 7, nl = n & 127;
    const float* W = wp.p[layer * 8 + g];
    (layer == 0 ? Wt0 : Wt1)[li] = f2bf(W[k * 128 + nl]);
    if (li < 512) {
      const int gb = li >> 7, nbv = li & 127;
      const float* B = wp.p[layer * 8 + 4 + gb];
      (layer == 0 ? bias0 : bias1)[li] = B[nbv];
    }
  }
}

// ---------------------------------------------------------------------------
// FAT 2: blocks [0,GEMM_B) = layer-0 GEMM (A = x f32); [GEMM_B,+NBIN) = bin_fill
// ---------------------------------------------------------------------------
__global__ __launch_bounds__(512) void fat_gemm_fill(
    const float* __restrict__ x, const ushort* __restrict__ Wt0,
    const float* __restrict__ bias0,
    ushort* __restrict__ q_bf, ushort* __restrict__ s_bf,
    unsigned char* __restrict__ kv8,
    const unsigned* __restrict__ binbuf, const int* __restrict__ binCnt,
    int* __restrict__ row_start, int* __restrict__ colv)
{
  __shared__ char smem[128 * 256];
  const int t = threadIdx.x;
  if (blockIdx.x < GEMM_B) {
    gemm_body<1>(x, Wt0, bias0, q_bf, s_bf, kv8, NN, smem, blockIdx.x);
    return;
  }
  // ---- bin_fill role ----
  int* hist  = (int*)smem;          // 128
  int* scanb = hist + 128;          // 128
  int* cur   = scanb + 128;         // 128
  int* wred  = cur + 128;           // 8
  const int b = blockIdx.x - GEMM_B;
  int part = 0;
  for (int i = t; i < b; i += 512) part += min(binCnt[i], BINCAP);
  #pragma unroll
  for (int o = 32; o; o >>= 1) part += __shfl_xor(part, o, 64);
  if ((t & 63) == 0) wred[t >> 6] = part;
  const int n = min(binCnt[b], BINCAP);
  const unsigned* __restrict__ buf = binbuf + (size_t)b * BINCAP;
  if (t < 128) hist[t] = 0;
  __syncthreads();
  int binBase = 0;
  #pragma unroll
  for (int i = 0; i < 8; ++i) binBase += wred[i];
  if (b == NBIN - 1 && t == 0) row_start[NN] = binBase + n;
  for (int i = t; i < n; i += 512) atomicAdd(&hist[(buf[i] >> 16) & 127], 1);
  __syncthreads();
  if (t < 128) scanb[t] = hist[t];
  __syncthreads();
  for (int off = 1; off < 128; off <<= 1) {
    int a = (t >= off && t < 128) ? scanb[t - off] : 0;
    __syncthreads();
    if (t < 128) scanb[t] += a;
    __syncthreads();
  }
  if (t < 128) {
    const int node = b * 128 + t;
    const int base = binBase + scanb[t] - hist[t];   // exclusive
    if (node < NN) row_start[node] = base;
    cur[t] = base;
  }
  __syncthreads();
  for (int i = t; i < n; i += 512) {
    const unsigned v = buf[i];
    const int pos = atomicAdd(&cur[(v >> 16) & 127], 1);
    colv[pos] = (int)(v & 0xFFFFu);
  }
}

// standalone layer-1 GEMM (A = h bf16)
__global__ __launch_bounds__(512) void gemm_v2(
    const ushort* __restrict__ A, const ushort* __restrict__ Wt,
    const float* __restrict__ bias,
    ushort* __restrict__ q_bf, ushort* __restrict__ s_bf,
    unsigned char* __restrict__ kv8)
{
  __shared__ char As[128 * 256];
  gemm_body<0>(A, Wt, bias, q_bf, s_bf, kv8, NN, As, blockIdx.x);
}

// ---------------------------------------------------------------------------
// Fused online attention + skip + LayerNorm. One node per wave (r13 code),
// 128-thread blocks (2 waves): completes the block-size curve.
// Measured: 16-wave 39%/84us, 4-wave 54%/64.6us -> block-granularity
// residency theory says smaller blocks backfill wave slots finer.
// ---------------------------------------------------------------------------
template <int WRITE_BF16>
__global__ __launch_bounds__(128) void edge_attn(
    const ushort* __restrict__ q_bf, const ushort* __restrict__ s_bf,
    const unsigned char* __restrict__ kv8,
    const int* __restrict__ row_start, const int* __restrict__ colv,
    const float* __restrict__ gamma, const float* __restrict__ beta,
    float* __restrict__ out_f, ushort* __restrict__ out_bf)
{
  const int wave = threadIdx.x >> 6, lane = threadIdx.x & 63;
  const int e8 = lane >> 3, l8 = lane & 7;
  const int n = blockIdx.x * 2 + wave;
  if (n >= NN) return;
  const int beg = row_start[n];
  const int deg = row_start[n + 1] - beg;

  int sn_own = 0;
  const bool small = (deg <= 64);
  if (small && deg > 0) sn_own = colv[beg + min(lane, deg - 1)];

  f32x2 qv[8];
  {
    const uint4 qa = *(const uint4*)(q_bf + (size_t)n * 128 + l8 * 16);
    const uint4 qb = *(const uint4*)(q_bf + (size_t)n * 128 + l8 * 16 + 8);
    qv[0] = unp2(qa.x); qv[1] = unp2(qa.y); qv[2] = unp2(qa.z); qv[3] = unp2(qa.w);
    qv[4] = unp2(qb.x); qv[5] = unp2(qb.y); qv[6] = unp2(qb.z); qv[7] = unp2(qb.w);
  }

  f32x2 acc2[8];
  #pragma unroll
  for (int j = 0; j < 8; ++j) acc2[j] = (f32x2){0.f, 0.f};
  float den = 0.f;

  if (deg > 0) {
    // prologue: load group 0
    int ii = min(e8, deg - 1);
    int sn = small ? __shfl(sn_own, ii, 64) : colv[beg + ii];
    const unsigned char* kvp = kv8 + (size_t)sn * 256 + l8 * 16;
    uint4 kw = *(const uint4*)kvp;
    uint4 vw = *(const uint4*)(kvp + 128);

    for (int base = 0; base < deg; base += 8) {
      // prefetch group base+8 (uniform gate -> no wasted traffic)
      uint4 kwn = kw, vwn = vw;
      if (base + 8 < deg) {
        const int iN = min(base + 8 + e8, deg - 1);
        const int snn = small ? __shfl(sn_own, iN, 64) : colv[beg + iN];
        const unsigned char* kvpn = kv8 + (size_t)snn * 256 + l8 * 16;
        kwn = *(const uint4*)kvpn;
        vwn = *(const uint4*)(kvpn + 128);
      }
      // compute current group
      const int i = base + e8;
      f32x2 p2 = __builtin_amdgcn_cvt_pk_f32_fp8((int)kw.x, false) * qv[0];
      p2 += __builtin_amdgcn_cvt_pk_f32_fp8((int)kw.x, true)  * qv[1];
      p2 += __builtin_amdgcn_cvt_pk_f32_fp8((int)kw.y, false) * qv[2];
      p2 += __builtin_amdgcn_cvt_pk_f32_fp8((int)kw.y, true)  * qv[3];
      p2 += __builtin_amdgcn_cvt_pk_f32_fp8((int)kw.z, false) * qv[4];
      p2 += __builtin_amdgcn_cvt_pk_f32_fp8((int)kw.z, true)  * qv[5];
      p2 += __builtin_amdgcn_cvt_pk_f32_fp8((int)kw.w, false) * qv[6];
      p2 += __builtin_amdgcn_cvt_pk_f32_fp8((int)kw.w, true)  * qv[7];
      float p = p2.x + p2.y;
      p += __shfl_xor(p, 1, 64);
      p += __shfl_xor(p, 2, 64);
      const float e = (i < deg) ? __expf(p * 0.125f) : 0.f;
      den += e;
      const f32x2 e2 = (f32x2){e, e};
      acc2[0] += __builtin_amdgcn_cvt_pk_f32_fp8((int)vw.x, false) * e2;
      acc2[1] += __builtin_amdgcn_cvt_pk_f32_fp8((int)vw.x, true)  * e2;
      acc2[2] += __builtin_amdgcn_cvt_pk_f32_fp8((int)vw.y, false) * e2;
      acc2[3] += __builtin_amdgcn_cvt_pk_f32_fp8((int)vw.y, true)  * e2;
      acc2[4] += __builtin_amdgcn_cvt_pk_f32_fp8((int)vw.z, false) * e2;
      acc2[5] += __builtin_amdgcn_cvt_pk_f32_fp8((int)vw.z, true)  * e2;
      acc2[6] += __builtin_amdgcn_cvt_pk_f32_fp8((int)vw.w, false) * e2;
      acc2[7] += __builtin_amdgcn_cvt_pk_f32_fp8((int)vw.w, true)  * e2;
      kw = kwn; vw = vwn;
    }
  }

  #pragma unroll
  for (int off = 8; off <= 32; off <<= 1) {
    den += __shfl_xor(den, off, 64);
    #pragma unroll
    for (int j = 0; j < 8; ++j) {
      acc2[j].x += __shfl_xor(acc2[j].x, off, 64);
      acc2[j].y += __shfl_xor(acc2[j].y, off, 64);
    }
  }

  const float rden = (deg > 0) ? 1.f / den : 0.f;
  float o[16], s1 = 0.f, s2 = 0.f;
  {
    const uint4 ra = *(const uint4*)(s_bf + (size_t)n * 128 + l8 * 16);
    const uint4 rb = *(const uint4*)(s_bf + (size_t)n * 128 + l8 * 16 + 8);
    f32x2 sv[8];
    sv[0] = unp2(ra.x); sv[1] = unp2(ra.y); sv[2] = unp2(ra.z); sv[3] = unp2(ra.w);
    sv[4] = unp2(rb.x); sv[5] = unp2(rb.y); sv[6] = unp2(rb.z); sv[7] = unp2(rb.w);
    #pragma unroll
    for (int j = 0; j < 8; ++j) {
      const float a = acc2[j].x * rden + sv[j].x;
      const float b = acc2[j].y * rden + sv[j].y;
      o[2 * j] = a; o[2 * j + 1] = b;
      s1 += a + b; s2 += a * a + b * b;
    }
  }
  #pragma unroll
  for (int off = 1; off <= 4; off <<= 1) {
    s1 += __shfl_xor(s1, off, 64);
    s2 += __shfl_xor(s2, off, 64);
  }
  const float mean = s1 * (1.f / 128.f);
  const float var  = s2 * (1.f / 128.f) - mean * mean;
  const float rs   = rsqrtf(fmaxf(var, 0.f) + 1e-5f);
  if (e8 == 0) {
    const int cbase = l8 * 16;
    #pragma unroll
    for (int jj = 0; jj < 4; ++jj) {
      const float4 g4 = *(const float4*)(gamma + cbase + jj * 4);
      const float4 b4 = *(const float4*)(beta + cbase + jj * 4);
      const float r0 = g4.x * ((o[jj*4+0] - mean) * rs) + b4.x;
      const float r1 = g4.y * ((o[jj*4+1] - mean) * rs) + b4.y;
      const float r2 = g4.z * ((o[jj*4+2] - mean) * rs) + b4.z;
      const float r3 = g4.w * ((o[jj*4+3] - mean) * rs) + b4.w;
      if (WRITE_BF16) {
        ushort4 u4; u4.x = f2bf(r0); u4.y = f2bf(r1); u4.z = f2bf(r2); u4.w = f2bf(r3);
        *(ushort4*)(out_bf + (size_t)n * 128 + cbase + jj * 4) = u4;
      } else {
        *(float4*)(out_f + (size_t)n * 128 + cbase + jj * 4) = make_float4(r0, r1, r2, r3);
      }
    }
  }
}

// ---------------------------------------------------------------------------
extern "C" void kernel_launch(void* const* d_in, const int* in_sizes, int n_in,
                              void* d_out, int out_size, void* d_ws, size_t ws_size,
                              hipStream_t stream)
{
  const float* x  = (const float*)d_in[0];
  const int*   ei = (const int*)d_in[1];
  const float* P[20];
  for (int i = 0; i < 20; ++i) P[i] = (const float*)d_in[2 + i];

  char* w = (char*)d_ws;
  ushort* q_bf = (ushort*)w; w += (size_t)NN * 128 * 2;          // 12.8 MB
  ushort* s_bf = (ushort*)w; w += (size_t)NN * 128 * 2;          // 12.8 MB
  unsigned char* kv8 = (unsigned char*)w; w += (size_t)NN * 256; // 12.8 MB
  ushort* h_bf = (ushort*)w; w += (size_t)NN * 128 * 2;          // 12.8 MB
  unsigned* binbuf = (unsigned*)w; w += (size_t)NBIN * BINCAP * 4; // 7.2 MB
  int* colv = (int*)w;      w += (size_t)NE * 4;                 // 6.4 MB
  ushort* Wt0 = (ushort*)w; w += (size_t)512 * 128 * 2;
  ushort* Wt1 = (ushort*)w; w += (size_t)512 * 128 * 2;
  float* bias0 = (float*)w; w += 512 * 4;
  float* bias1 = (float*)w; w += 512 * 4;
  int* row_start = (int*)w; w += (size_t)(NN + 1) * 4;
  int* binCnt = (int*)w;    w += (size_t)NBIN * 4;

  const int* srcv = ei;
  const int* dstv = ei + NE;

  WPtrs wp;
  for (int i = 0; i < 8; ++i)  wp.p[i] = P[i];          // layer 0
  for (int i = 0; i < 8; ++i)  wp.p[8 + i] = P[10 + i]; // layer 1

  hipMemsetAsync(binCnt, 0, (size_t)NBIN * 4, stream);

  // FAT1: edge scatter || weight prep
  fat_scatter_prep<<<SCAT_B + PREP_B, 512, 0, stream>>>(
      srcv, dstv, binCnt, binbuf, wp, Wt0, Wt1, bias0, bias1);

  // FAT2: layer-0 GEMM || CSR fill
  fat_gemm_fill<<<GEMM_B + NBIN, 512, 0, stream>>>(
      x, Wt0, bias0, q_bf, s_bf, kv8, binbuf, binCnt, row_start, colv);

  const int agrid = (NN + 1) / 2;   // 2 waves/block, 1 node per wave

  edge_attn<1><<<agrid, 128, 0, stream>>>(q_bf, s_bf, kv8, row_start, colv,
                                          P[8], P[9], nullptr, h_bf);
  gemm_v2<<<GEMM_B, 512, 0, stream>>>(h_bf, Wt1, bias1, q_bf, s_bf, kv8);
  edge_attn<0><<<agrid, 128, 0, stream>>>(q_bf, s_bf, kv8, row_start, colv,
                                          P[18], P[19], (float*)d_out, nullptr);
}